// Round 3
// baseline (272.505 us; speedup 1.0000x reference)
//
#include <hip/hip_runtime.h>
#include <math.h>

// Problem constants (reference: x_l [16, 1, 1536, 1536] fp32, PATCH=3, ALPHA=1)
#define IMG_W 1536
#define IMG_H 1536
#define NIMG  16
#define ROWS_PER_BLOCK 8   // output rows per thread (rolling window)

typedef float f32x4 __attribute__((ext_vector_type(4)));  // native vec for NT store

// out(h,w) = sum_k v_k*exp(-v_k) / sum_k exp(-v_k) over the 3x3 zero-padded
// neighborhood (the reference's "-x^2" shift cancels in softmax; padded taps
// contribute v=0 -> e=1, ve=0).
//
// Structure: thread owns a 4-wide column group and ROWS_PER_BLOCK output rows.
// Per input row: one float4 load, 4 exps, horizontal 3-sums using lane+-1
// shuffles for the boundary e/ve (lanes 0/63 do one guarded scalar halo load).
// Vertical 3-sum via a 3-deep rolling register window -> each input row is
// loaded exactly once per block (plus 2 halo rows shared with the vertically
// adjacent blocks, likely L2/L3 hits).
__global__ __launch_bounds__(128)
void WeightedAverage_55551107006568_kernel(const float* __restrict__ x,
                                           float* __restrict__ out) {
    const int lane = threadIdx.x & 63;
    const int g  = blockIdx.x * 128 + threadIdx.x;   // column-group index
    const int w0 = g << 2;                           // first owned column
    const int h0 = blockIdx.y * ROWS_PER_BLOCK;
    const size_t plane = (size_t)blockIdx.z * ((size_t)IMG_H * IMG_W);
    const float* xp = x + plane;
    float* op = out + plane;

    float hE[3][4], hVE[3][4];   // horizontal 3-sums for last 3 rows

#pragma unroll
    for (int i = 0; i < ROWS_PER_BLOCK + 2; ++i) {
        const int r = h0 - 1 + i;        // input row (block-uniform)
        const int s = i % 3;             // rolling slot (constant after unroll)

        if (r < 0 || r >= IMG_H) {
            // fully padded row: every tap v=0 -> e=1, ve=0 -> hE=3, hVE=0
#pragma unroll
            for (int p = 0; p < 4; ++p) { hE[s][p] = 3.f; hVE[s][p] = 0.f; }
        } else {
            const float* rp = xp + (size_t)r * IMG_W + w0;
            const f32x4 m = *(const f32x4*)rp;
            const float e0 = __expf(-m.x), e1 = __expf(-m.y);
            const float e2 = __expf(-m.z), e3 = __expf(-m.w);
            const float v0 = m.x * e0, v1 = m.y * e1;
            const float v2 = m.z * e2, v3 = m.w * e3;
            // boundary columns from neighbor lanes (uniform control flow here)
            float eL = __shfl_up(e3, 1),   vL = __shfl_up(v3, 1);
            float eR = __shfl_down(e0, 1), vR = __shfl_down(v0, 1);
            if (lane == 0) {               // left edge of this wave's 256 cols
                if (w0 == 0) { eL = 1.f; vL = 0.f; }       // image pad
                else { const float t = rp[-1]; eL = __expf(-t); vL = t * eL; }
            }
            if (lane == 63) {              // right edge of this wave's cols
                if (w0 + 4 >= IMG_W) { eR = 1.f; vR = 0.f; } // image pad
                else { const float t = rp[4]; eR = __expf(-t); vR = t * eR; }
            }
            hE[s][0] = eL + e0 + e1;  hVE[s][0] = vL + v0 + v1;
            hE[s][1] = e0 + e1 + e2;  hVE[s][1] = v0 + v1 + v2;
            hE[s][2] = e1 + e2 + e3;  hVE[s][2] = v1 + v2 + v3;
            hE[s][3] = e2 + e3 + eR;  hVE[s][3] = v2 + v3 + vR;
        }

        if (i >= 2) {
            const int ro = r - 1;        // output row, in [h0, h0+R)
            f32x4 o;
#pragma unroll
            for (int p = 0; p < 4; ++p) {
                const float den = hE[0][p] + hE[1][p] + hE[2][p];
                const float num = hVE[0][p] + hVE[1][p] + hVE[2][p];
                o[p] = __fdividef(num, den);
            }
            // write-once output: nontemporal so it doesn't evict input rows
            __builtin_nontemporal_store(o, (f32x4*)(op + (size_t)ro * IMG_W + w0));
        }
    }
}

extern "C" void kernel_launch(void* const* d_in, const int* in_sizes, int n_in,
                              void* d_out, int out_size, void* d_ws, size_t ws_size,
                              hipStream_t stream) {
    const float* x = (const float*)d_in[0];
    float* out = (float*)d_out;
    dim3 grid(IMG_W / (128 * 4), IMG_H / ROWS_PER_BLOCK, NIMG); // (3, 192, 16)
    dim3 block(128, 1, 1);
    WeightedAverage_55551107006568_kernel<<<grid, block, 0, stream>>>(x, out);
}

// Round 4
// 259.019 us; speedup vs baseline: 1.0521x; 1.0521x over previous
//
#include <hip/hip_runtime.h>
#include <math.h>

// Problem constants (reference: x_l [16, 1, 1536, 1536] fp32, PATCH=3, ALPHA=1)
#define IMG_W 1536
#define IMG_H 1536
#define NIMG  16
#define RPB 8                       // output rows per thread
#define NROWS (RPB + 2)             // loaded rows (incl. vertical halo)

typedef float f32x4 __attribute__((ext_vector_type(4)));

// out(h,w) = sum_k v_k*exp(-v_k) / sum_k exp(-v_k) over the 3x3 zero-padded
// neighborhood (the "-x^2" shift cancels in softmax; padded taps: e=1, ve=0).
//
// R4 change vs R3: all NROWS row-vectors (and edge-lane halo scalars) are
// loaded into explicit register arrays BEFORE any compute, so the wave keeps
// ~10 outstanding global loads (R3's rolling window compressed to 24 VGPRs and
// serialized the loads -> latency-bound at 2.4 TB/s).
__global__ __launch_bounds__(128)
void WeightedAverage_55551107006568_kernel(const float* __restrict__ x,
                                           float* __restrict__ out) {
    const int lane = threadIdx.x & 63;
    const int g  = blockIdx.x * 128 + threadIdx.x;   // column-group index
    const int w0 = g << 2;                           // first owned column
    const int h0 = blockIdx.y * RPB;
    const size_t plane = (size_t)blockIdx.z * ((size_t)IMG_H * IMG_W);
    const float* xp = x + plane;
    float* op = out + plane;

    // ---- phase 1: issue ALL loads (10 outstanding vmcnt items) ----
    f32x4 m[NROWS];
    float hl[NROWS], hr[NROWS];
    const bool leftEdge  = (w0 == 0);
    const bool rightEdge = (w0 + 4 >= IMG_W);
#pragma unroll
    for (int i = 0; i < NROWS; ++i) {
        const int r = h0 - 1 + i;                    // block-uniform row index
        const bool rok = (r >= 0) && (r < IMG_H);
        f32x4 mm = {0.f, 0.f, 0.f, 0.f};
        float hlv = 0.f, hrv = 0.f;                  // 0 -> e=1, ve=0 (pad)
        if (rok) {
            const float* rp = xp + (size_t)r * IMG_W + w0;
            mm = *(const f32x4*)rp;
            if (lane == 0  && !leftEdge)  hlv = rp[-1];
            if (lane == 63 && !rightEdge) hrv = rp[4];
        }
        m[i] = mm; hl[i] = hlv; hr[i] = hrv;
    }

    // ---- phase 2: per-row horizontal 3-sums, rolling vertical 3-sum ----
    float hE[3][4], hVE[3][4];
#pragma unroll
    for (int i = 0; i < NROWS; ++i) {
        const int r = h0 - 1 + i;
        const int s = i % 3;
        if (r < 0 || r >= IMG_H) {
            // fully padded row: all taps v=0 -> e=1 -> hE=3, hVE=0
#pragma unroll
            for (int p = 0; p < 4; ++p) { hE[s][p] = 3.f; hVE[s][p] = 0.f; }
        } else {
            const f32x4 mm = m[i];
            const float e0 = __expf(-mm.x), e1 = __expf(-mm.y);
            const float e2 = __expf(-mm.z), e3 = __expf(-mm.w);
            const float v0 = mm.x * e0, v1 = mm.y * e1;
            const float v2 = mm.z * e2, v3 = mm.w * e3;
            // boundary columns: neighbor lanes, or own halo scalar on lanes 0/63
            const float e3s = __shfl_up(e3, 1),   v3s = __shfl_up(v3, 1);
            const float e0s = __shfl_down(e0, 1), v0s = __shfl_down(v0, 1);
            const float el0 = __expf(-hl[i]);     // only lane 0's value used
            const float er0 = __expf(-hr[i]);     // only lane 63's value used
            const float eL = (lane == 0)  ? el0 : e3s;
            const float vL = (lane == 0)  ? hl[i] * el0 : v3s;
            const float eR = (lane == 63) ? er0 : e0s;
            const float vR = (lane == 63) ? hr[i] * er0 : v0s;
            hE[s][0] = eL + e0 + e1;  hVE[s][0] = vL + v0 + v1;
            hE[s][1] = e0 + e1 + e2;  hVE[s][1] = v0 + v1 + v2;
            hE[s][2] = e1 + e2 + e3;  hVE[s][2] = v1 + v2 + v3;
            hE[s][3] = e2 + e3 + eR;  hVE[s][3] = v2 + v3 + vR;
        }

        if (i >= 2) {
            const int ro = h0 + i - 2;               // output row
            f32x4 o;
#pragma unroll
            for (int p = 0; p < 4; ++p) {
                const float den = hE[0][p] + hE[1][p] + hE[2][p];
                const float num = hVE[0][p] + hVE[1][p] + hVE[2][p];
                o[p] = __fdividef(num, den);
            }
            // write-once output: nontemporal so it doesn't evict input from L2/L3
            __builtin_nontemporal_store(o, (f32x4*)(op + (size_t)ro * IMG_W + w0));
        }
    }
}

extern "C" void kernel_launch(void* const* d_in, const int* in_sizes, int n_in,
                              void* d_out, int out_size, void* d_ws, size_t ws_size,
                              hipStream_t stream) {
    const float* x = (const float*)d_in[0];
    float* out = (float*)d_out;
    dim3 grid(IMG_W / (128 * 4), IMG_H / RPB, NIMG);   // (3, 192, 16)
    dim3 block(128, 1, 1);
    WeightedAverage_55551107006568_kernel<<<grid, block, 0, stream>>>(x, out);
}